// Round 6
// baseline (790.212 us; speedup 1.0000x reference)
//
#include <hip/hip_runtime.h>
#include <hip/hip_bf16.h>

// Problem constants
#define BB 32
#define NNODE 512
#define EE 128
#define MAXDEG 64  // fixed edge slots per row (binomial(512,.05) max ~53)

typedef float v2f __attribute__((ext_vector_type(2)));
typedef __fp16 h2 __attribute__((ext_vector_type(2)));  // matches cvt_pkrtz
__device__ __forceinline__ v2f fma2(v2f a, v2f b, v2f c) {
  return __builtin_elementwise_fma(a, b, c);
}

// Fast gates: v_rcp_f32 instead of full-precision divide (~1ulp).
__device__ __forceinline__ float sigm_fast(float x) {
  return __builtin_amdgcn_rcpf(1.0f + __expf(-x));
}
__device__ __forceinline__ float tanh_fast(float x) {
  x = fminf(20.f, fmaxf(-20.f, x));
  float t = __expf(-2.f * x);
  return (1.f - t) * __builtin_amdgcn_rcpf(1.f + t);
}

// ---------------------------------------------------------------------------
// wh[2s|2s+1][:, 0:64] = relu(LIT @ W_lit); xp = SEM @ gru_k + gru_b[0]
// grid 1024 x 64.
__global__ __launch_bounds__(64, 1) void k_data(
    const float* __restrict__ lit1, const float* __restrict__ sem1,
    const float* __restrict__ lit2, const float* __restrict__ sem2,
    const float* __restrict__ wl1, const float* __restrict__ gk1,
    const float* __restrict__ gb1, const float* __restrict__ wl2,
    const float* __restrict__ gk2, const float* __restrict__ gb2,
    float* __restrict__ wh, float* __restrict__ xp) {
  __shared__ float stage[64 * 65];
  int bid = blockIdx.x;
  int rowblk = bid >> 1, half = bid & 1;
  int grow0 = rowblk * 64;
  int side = grow0 >> 14;
  int lrow0 = grow0 & 16383;
  const float* lit = side ? lit2 : lit1;
  const float* sem = side ? sem2 : sem1;
  const float* wl = side ? wl2 : wl1;
  const float* gk = side ? gk2 : gk1;
  const float* gb = side ? gb2 : gb1;
  int tid = threadIdx.x;

  {
    const float4* lit4 = (const float4*)(lit + (size_t)lrow0 * 64);
#pragma unroll
    for (int p = 0; p < 16; ++p) {
      int s = p * 64 + tid;
      int r = s >> 4, q = s & 15;
      float4 v = lit4[r * 16 + q];
      stage[r * 65 + 4 * q + 0] = v.x;
      stage[r * 65 + 4 * q + 1] = v.y;
      stage[r * 65 + 4 * q + 2] = v.z;
      stage[r * 65 + 4 * q + 3] = v.w;
    }
    v2f acc[16];
#pragma unroll
    for (int c = 0; c < 16; ++c) acc[c] = (v2f){0.f, 0.f};
    const float4* wl4 = (const float4*)wl;  // [64][16] f4
    for (int i = 0; i < 64; ++i) {
      float rv = stage[tid * 65 + i];
      v2f rv2 = {rv, rv};
#pragma unroll
      for (int c4 = 0; c4 < 8; ++c4) {
        float4 w = wl4[i * 16 + half * 8 + c4];
        acc[2 * c4 + 0] = fma2(rv2, (v2f){w.x, w.y}, acc[2 * c4 + 0]);
        acc[2 * c4 + 1] = fma2(rv2, (v2f){w.z, w.w}, acc[2 * c4 + 1]);
      }
    }
    float4* w0 = (float4*)wh + ((size_t)(2 * side) * 16384 + lrow0 + tid) * 32;
    float4* w1 =
        (float4*)wh + ((size_t)(2 * side + 1) * 16384 + lrow0 + tid) * 32;
#pragma unroll
    for (int c4 = 0; c4 < 8; ++c4) {
      float4 o;
      o.x = fmaxf(acc[2 * c4].x, 0.f);
      o.y = fmaxf(acc[2 * c4].y, 0.f);
      o.z = fmaxf(acc[2 * c4 + 1].x, 0.f);
      o.w = fmaxf(acc[2 * c4 + 1].y, 0.f);
      w0[half * 8 + c4] = o;
      w1[half * 8 + c4] = o;
    }
  }
  {
    const float4* sem4 = (const float4*)(sem + (size_t)lrow0 * 64);
#pragma unroll
    for (int p = 0; p < 16; ++p) {
      int s = p * 64 + tid;
      int r = s >> 4, q = s & 15;
      float4 v = sem4[r * 16 + q];
      stage[r * 65 + 4 * q + 0] = v.x;
      stage[r * 65 + 4 * q + 1] = v.y;
      stage[r * 65 + 4 * q + 2] = v.z;
      stage[r * 65 + 4 * q + 3] = v.w;
    }
    v2f acc2[48];
#pragma unroll
    for (int c = 0; c < 48; ++c)
      acc2[c] = (v2f){gb[half * 96 + 2 * c], gb[half * 96 + 2 * c + 1]};
    const float4* gk4 = (const float4*)gk;  // [64][48] f4
    for (int i = 0; i < 64; ++i) {
      float rv = stage[tid * 65 + i];
      v2f rv2 = {rv, rv};
#pragma unroll
      for (int c4 = 0; c4 < 24; ++c4) {
        float4 w = gk4[i * 48 + half * 24 + c4];
        acc2[2 * c4 + 0] = fma2(rv2, (v2f){w.x, w.y}, acc2[2 * c4 + 0]);
        acc2[2 * c4 + 1] = fma2(rv2, (v2f){w.z, w.w}, acc2[2 * c4 + 1]);
      }
    }
    float4* xp4 = (float4*)xp;
    int grow = grow0 + tid;
#pragma unroll
    for (int c4 = 0; c4 < 24; ++c4) {
      float4 o;
      o.x = acc2[2 * c4].x;
      o.y = acc2[2 * c4].y;
      o.z = acc2[2 * c4 + 1].x;
      o.w = acc2[2 * c4 + 1].y;
      xp4[(size_t)grow * 48 + half * 24 + c4] = o;
    }
  }
}

// ---------------------------------------------------------------------------
// CSR/CSC build (standalone so the GRU kernel gets a full register budget).
// grid 1024 x 256.
__global__ __launch_bounds__(256, 1) void k_csr(
    const float* __restrict__ A1, const float* __restrict__ A2,
    int* __restrict__ counts, int* __restrict__ edges) {
  int bid = blockIdx.x;
  int t = threadIdx.x;
  if (bid < 512) {
    int s = bid >> 8, b = (bid >> 3) & 31, ch = bid & 7;
    const float* A = s ? A2 : A1;
    const float4* A4 = (const float4*)(A + ((size_t)b * 512 + ch * 64) * 512);
    __shared__ int crow[64];
    if (t < 64) crow[t] = 0;
    __syncthreads();
    int* efwd =
        edges + (size_t)(2 * s) * 1048576 + ((size_t)b * 512 + ch * 64) * 64;
#pragma unroll
    for (int it = 0; it < 32; ++it) {
      int idx = it * 256 + t;
      int r = idx >> 7, c4 = idx & 127;
      float4 v = A4[idx];
      float vv[4] = {v.x, v.y, v.z, v.w};
#pragma unroll
      for (int e = 0; e < 4; ++e) {
        if (vv[e] != 0.f) {
          int pos = atomicAdd(&crow[r], 1);
          if (pos < MAXDEG) efwd[r * 64 + pos] = 4 * c4 + e;
        }
      }
    }
    __syncthreads();
    if (t < 64)
      counts[(2 * s) * 16384 + b * 512 + ch * 64 + t] = min(crow[t], MAXDEG);
  } else {
    int bid2 = bid - 512;
    int s = bid2 >> 8, b = (bid2 >> 3) & 31, cch = bid2 & 7;
    const float* A = s ? A2 : A1;
    __shared__ int ccol[64];
    if (t < 64) ccol[t] = 0;
    __syncthreads();
    int lane = t & 63, rg = t >> 6;
    int c = cch * 64 + lane;
    int* erev = edges + (size_t)(2 * s + 1) * 1048576 + ((size_t)b * 512) * 64;
    const float* Ab = A + (size_t)b * 512 * 512;
    for (int it = 0; it < 128; ++it) {
      int r = it * 4 + rg;
      float a = Ab[(size_t)r * 512 + c];
      if (a != 0.f) {
        int pos = atomicAdd(&ccol[lane], 1);
        if (pos < MAXDEG) erev[(size_t)c * 64 + pos] = r;
      }
    }
    __syncthreads();
    if (t < 64)
      counts[(2 * s + 1) * 16384 + b * 512 + cch * 64 + t] =
          min(ccol[t], MAXDEG);
  }
}

// ---------------------------------------------------------------------------
// GRU scan, SINGLE-WAVE per sequence. Round-6 change: the round-3/5 step
// body lived in capture-by-reference LAMBDAS — if not fully inlined, every
// captured array (weights/bufs) must be memory-backed -> alloca stays in
// scratch (VGPR_Count 104/140 despite a 512 budget). Replaced with textual
// MACROS so the body is guaranteed inline and SROA promotes all arrays.
// f16 weight columns (96 h2 = 96 VGPRs) + f16 h-broadcast + v_dot2_f32_f16.
// grid 64 x 64.
#define LOADC(buf, tc)                                  \
  do {                                                  \
    const float* _src = xpr + (size_t)(tc) * 1536;      \
    _Pragma("unroll") for (int _q = 0; _q < 8; ++_q) {  \
      buf[3 * _q + 0] = _src[_q * 192 + jj];            \
      buf[3 * _q + 1] = _src[_q * 192 + 64 + jj];       \
      buf[3 * _q + 2] = _src[_q * 192 + 128 + jj];      \
    }                                                   \
  } while (0)

#define GSTEP(buf, tt, t)                                            \
  do {                                                               \
    float _cxz = buf[3 * (tt) + 0];                                  \
    float _cxr = buf[3 * (tt) + 1];                                  \
    float _cxv = buf[3 * (tt) + 2];                                  \
    const uint4* _hb = (const uint4*)hsh;                            \
    float _az0 = 0.f, _az1 = 0.f, _ar0 = 0.f, _ar1 = 0.f;            \
    float _av0 = 0.f, _av1 = 0.f;                                    \
    _Pragma("unroll") for (int _c = 0; _c < 8; ++_c) {               \
      uint4 _hv = _hb[_c];                                           \
      h2 _p0 = __builtin_bit_cast(h2, _hv.x);                        \
      h2 _p1 = __builtin_bit_cast(h2, _hv.y);                        \
      h2 _p2 = __builtin_bit_cast(h2, _hv.z);                        \
      h2 _p3 = __builtin_bit_cast(h2, _hv.w);                        \
      _az0 = __builtin_amdgcn_fdot2(_p0, wz[4 * _c + 0], _az0, false); \
      _az1 = __builtin_amdgcn_fdot2(_p1, wz[4 * _c + 1], _az1, false); \
      _az0 = __builtin_amdgcn_fdot2(_p2, wz[4 * _c + 2], _az0, false); \
      _az1 = __builtin_amdgcn_fdot2(_p3, wz[4 * _c + 3], _az1, false); \
      _ar0 = __builtin_amdgcn_fdot2(_p0, wr[4 * _c + 0], _ar0, false); \
      _ar1 = __builtin_amdgcn_fdot2(_p1, wr[4 * _c + 1], _ar1, false); \
      _ar0 = __builtin_amdgcn_fdot2(_p2, wr[4 * _c + 2], _ar0, false); \
      _ar1 = __builtin_amdgcn_fdot2(_p3, wr[4 * _c + 3], _ar1, false); \
      _av0 = __builtin_amdgcn_fdot2(_p0, wv[4 * _c + 0], _av0, false); \
      _av1 = __builtin_amdgcn_fdot2(_p1, wv[4 * _c + 1], _av1, false); \
      _av0 = __builtin_amdgcn_fdot2(_p2, wv[4 * _c + 2], _av0, false); \
      _av1 = __builtin_amdgcn_fdot2(_p3, wv[4 * _c + 3], _av1, false); \
    }                                                                \
    float _z = sigm_fast(_cxz + _az0 + _az1 + bz);                   \
    float _r = sigm_fast(_cxr + _ar0 + _ar1 + brr);                  \
    float _hh = tanh_fast(_cxv + _r * (_av0 + _av1 + bv));           \
    float _hnew = fmaf(_z, hold - _hh, _hh);                         \
    hold = _hnew;                                                    \
    __builtin_amdgcn_sched_barrier(0);                               \
    hsh[jj] = (__fp16)_hnew;                                         \
    float _rv = fmaxf(_hnew, 0.f);                                   \
    w0[(size_t)(t) * 128] = _rv;                                     \
    w1[(size_t)(t) * 128] = _rv;                                     \
  } while (0)

__global__ __launch_bounds__(64, 1) void k_gru(
    const float* __restrict__ xp, const float* __restrict__ rk1,
    const float* __restrict__ b1, const float* __restrict__ rk2,
    const float* __restrict__ b2, float* __restrict__ wh) {
  int blk = blockIdx.x;
  int side = blk >> 5, b = blk & 31;
  int jj = threadIdx.x;  // output index 0..63
  const float* rk = side ? rk2 : rk1;
  const float* bbp = side ? b2 : b1;
  // f16 weight column for this lane: pair k covers rows 2k,2k+1 of rk.
  h2 wz[32], wr[32], wv[32];
#pragma unroll
  for (int k = 0; k < 32; ++k) {
    const float* r0 = rk + (size_t)(2 * k) * 192 + jj;
    const float* r1 = r0 + 192;
    wz[k] = __builtin_amdgcn_cvt_pkrtz(r0[0], r1[0]);
    wr[k] = __builtin_amdgcn_cvt_pkrtz(r0[64], r1[64]);
    wv[k] = __builtin_amdgcn_cvt_pkrtz(r0[128], r1[128]);
  }
  float bz = bbp[192 + jj], brr = bbp[192 + 64 + jj], bv = bbp[192 + 128 + jj];

  __shared__ alignas(16) __fp16 hsh[64];
  hsh[jj] = (__fp16)0.f;
  float hold = 0.f;

  const float* xpr = xp + (size_t)(side * 16384 + b * 512) * 192;
  float* w0 = wh + ((size_t)(2 * side) * 16384 + b * 512) * 128 + 64 + jj;
  float* w1 = wh + ((size_t)(2 * side + 1) * 16384 + b * 512) * 128 + 64 + jj;

  float bufA[24], bufB[24];
  LOADC(bufA, 0);
  for (int tc2 = 0; tc2 < 32; ++tc2) {  // 64 chunks of 8 steps, paired A/B
    int tcA = 2 * tc2, tcB = 2 * tc2 + 1;
    LOADC(bufB, tcB);  // prefetch while computing A
#pragma unroll
    for (int tt = 0; tt < 8; ++tt) GSTEP(bufA, tt, tcA * 8 + tt);
    if (tcB + 1 < 64) LOADC(bufA, tcB + 1);  // prefetch while computing B
#pragma unroll
    for (int tt = 0; tt < 8; ++tt) GSTEP(bufB, tt, tcB * 8 + tt);
  }
}

// ---------------------------------------------------------------------------
// whg (PACKED BF16: uint = 2 cols) = wh @ W_g; ah1/ah2 fp32.
// grid 1024 x 64; one wave = 64 rows. XCD-swizzled (blockIdx%8 = XCD): all 8
// blocks of one (st,b) group land on the same XCD so whg stays in its L2.
__global__ __launch_bounds__(64, 1) void k_whg(
    const float* __restrict__ wh, const float* __restrict__ Wg,
    const float* __restrict__ a1w, const float* __restrict__ a1b,
    const float* __restrict__ a2w, const float* __restrict__ a2b,
    unsigned int* __restrict__ whg, float* __restrict__ ah1,
    float* __restrict__ ah2) {
  __shared__ float stage[64 * 129];
  int B = blockIdx.x;
  int xcd = B & 7, slot = B >> 3;   // slot 0..127
  int grp = xcd + 8 * (slot >> 3);  // (st,b) group 0..127
  int sub = slot & 7;               // 64-row tile within group
  int rowbase = grp * 512 + sub * 64;
  int tid = threadIdx.x;
  const float4* wh4 = (const float4*)(wh + (size_t)rowbase * 128);
#pragma unroll
  for (int p = 0; p < 32; ++p) {
    int s = p * 64 + tid;
    int r = s >> 5, q = s & 31;
    float4 v = wh4[r * 32 + q];
    stage[r * 129 + 4 * q + 0] = v.x;
    stage[r * 129 + 4 * q + 1] = v.y;
    stage[r * 129 + 4 * q + 2] = v.z;
    stage[r * 129 + 4 * q + 3] = v.w;
  }
  v2f acc[64];
#pragma unroll
  for (int c = 0; c < 64; ++c) acc[c] = (v2f){0.f, 0.f};
  float p1 = a1b[0], p2 = a2b[0];
  const float4* Wg4 = (const float4*)Wg;  // [128][32] f4
  for (int i = 0; i < 128; ++i) {
    float rv = stage[tid * 129 + i];
    v2f rv2 = {rv, rv};
    p1 = fmaf(rv, a1w[i], p1);
    p2 = fmaf(rv, a2w[i], p2);
#pragma unroll
    for (int c4 = 0; c4 < 32; ++c4) {
      float4 w = Wg4[i * 32 + c4];
      acc[2 * c4 + 0] = fma2(rv2, (v2f){w.x, w.y}, acc[2 * c4 + 0]);
      acc[2 * c4 + 1] = fma2(rv2, (v2f){w.z, w.w}, acc[2 * c4 + 1]);
    }
  }
  int grow = rowbase + tid;
  uint2* o2 = (uint2*)(whg + (size_t)grow * 64);
#pragma unroll
  for (int c4 = 0; c4 < 32; c4 += 2) {
    __hip_bfloat162 A =
        __float22bfloat162_rn(make_float2(acc[c4].x, acc[c4].y));
    __hip_bfloat162 Bv =
        __float22bfloat162_rn(make_float2(acc[c4 + 1].x, acc[c4 + 1].y));
    uint2 pk;
    pk.x = *(unsigned int*)&A;
    pk.y = *(unsigned int*)&Bv;
    o2[c4 >> 1] = pk;
  }
  ah1[grow] = p1;
  ah2[grow] = p2;
}

// ---------------------------------------------------------------------------
// Per-row edge softmax + aggregate + elu. One wave per row, 4 rows per block.
// Lane-parallel setup; shfl-broadcast gather; whg is PACKED BF16 so each lane
// reads ONE 4B uint (2 cols) per edge — half the loads/bytes of fp32.
// XCD-swizzled to match k_whg. grid 16384 x 256.
__global__ __launch_bounds__(256, 1) void k_attn(
    float* __restrict__ wh, const unsigned int* __restrict__ whg,
    const float* __restrict__ ah1, const float* __restrict__ ah2,
    const int* __restrict__ counts, const int* __restrict__ edges) {
  int B = blockIdx.x;
  int xcd = B & 7, slot = B >> 3;   // slot 0..2047
  int grp = xcd + 8 * (slot >> 7);  // group 0..127
  int sub = slot & 127;             // 0..127 (4 rows each)
  int row = grp * 512 + sub * 4 + (threadIdx.x >> 6);
  int lane = threadIdx.x & 63;
  int st = row >> 14;
  int loc = row & 16383;
  int base = row & ~511;
  int cnt = counts[row];
  const int* ed = edges + (size_t)st * 1048576 + (size_t)loc * 64;
  int jk = lane < cnt ? ed[lane] : 0;
  float a1v = ah1[row];
  float e = a1v + ah2[base + jk];
  e = e >= 0.f ? e : 0.2f * e;  // leaky_relu 0.2
  float w = lane < cnt ? __expf(e) : 0.f;
  float lsum = w;
#pragma unroll
  for (int off = 32; off; off >>= 1) lsum += __shfl_xor(lsum, off, 64);
  float inv = cnt > 0 ? 1.0f / lsum : 0.f;
  const unsigned int* wgb = whg + (size_t)base * 64;
  v2f a0 = {0.f, 0.f}, a1 = {0.f, 0.f}, a2 = {0.f, 0.f}, a3 = {0.f, 0.f};
  int k = 0;
  for (; k + 4 <= cnt; k += 4) {
    float w0 = __shfl(w, k, 64), w1 = __shfl(w, k + 1, 64);
    float w2 = __shfl(w, k + 2, 64), w3 = __shfl(w, k + 3, 64);
    int j0 = __shfl(jk, k, 64), j1 = __shfl(jk, k + 1, 64);
    int j2 = __shfl(jk, k + 2, 64), j3 = __shfl(jk, k + 3, 64);
    unsigned int d0 = wgb[(size_t)j0 * 64 + lane];
    unsigned int d1 = wgb[(size_t)j1 * 64 + lane];
    unsigned int d2 = wgb[(size_t)j2 * 64 + lane];
    unsigned int d3 = wgb[(size_t)j3 * 64 + lane];
    v2f v0 = {__uint_as_float(d0 << 16), __uint_as_float(d0 & 0xffff0000u)};
    v2f v1 = {__uint_as_float(d1 << 16), __uint_as_float(d1 & 0xffff0000u)};
    v2f v2 = {__uint_as_float(d2 << 16), __uint_as_float(d2 & 0xffff0000u)};
    v2f v3 = {__uint_as_float(d3 << 16), __uint_as_float(d3 & 0xffff0000u)};
    a0 = fma2((v2f){w0, w0}, v0, a0);
    a1 = fma2((v2f){w1, w1}, v1, a1);
    a2 = fma2((v2f){w2, w2}, v2, a2);
    a3 = fma2((v2f){w3, w3}, v3, a3);
  }
  for (; k < cnt; ++k) {
    float w0 = __shfl(w, k, 64);
    int j0 = __shfl(jk, k, 64);
    unsigned int d0 = wgb[(size_t)j0 * 64 + lane];
    v2f v0 = {__uint_as_float(d0 << 16), __uint_as_float(d0 & 0xffff0000u)};
    a0 = fma2((v2f){w0, w0}, v0, a0);
  }
  v2f acc = (a0 + a1) + (a2 + a3);
  // lane covers cols 2*lane, 2*lane+1
  float2* wr2 = (float2*)(wh + (size_t)row * 128);
  float2 old = wr2[lane];
  float o0 = old.x + acc.x * inv;
  float o1 = old.y + acc.y * inv;
  o0 = o0 > 0.f ? o0 : __expf(o0) - 1.f;  // elu
  o1 = o1 > 0.f ? o1 : __expf(o1) - 1.f;
  wr2[lane] = make_float2(o0, o1);
}

// ---------------------------------------------------------------------------
// Fused node-sum + output projection. grid 64 x 256. Block = (side,b).
__global__ __launch_bounds__(256, 1) void k_tail(const float* __restrict__ wh,
                                                 const float* __restrict__ Wout,
                                                 const float* __restrict__ bout,
                                                 float* __restrict__ e12) {
  int sb = blockIdx.x;
  int side = sb >> 5, b = sb & 31;
  int t = threadIdx.x;
  int c = t & 127, half = t >> 7;
  __shared__ float part[2][128];
  __shared__ float mid[128];
  size_t s0 = ((size_t)(2 * side) * 16384 + b * 512) * 128;
  size_t s1 = ((size_t)(2 * side + 1) * 16384 + b * 512) * 128;
  float sum = 0.f;
  int r0 = half * 256;
  for (int r = r0; r < r0 + 256; ++r) {
    sum += wh[s0 + (size_t)r * 128 + c] + wh[s1 + (size_t)r * 128 + c];
  }
  part[half][c] = sum;
  __syncthreads();
  if (t < 128) mid[t] = part[0][t] + part[1][t];
  __syncthreads();
  if (t < 64) {
    float acc = bout[t];
    for (int k2 = 0; k2 < 128; ++k2) acc = fmaf(mid[k2], Wout[k2 * 64 + t], acc);
    e12[sb * 64 + t] = acc;
  }
}

__global__ void k_cos(const float* __restrict__ e12, float* __restrict__ out) {
  int b = threadIdx.x;
  if (b >= 32) return;
  const float* e1 = e12 + b * 64;
  const float* e2 = e12 + 2048 + b * 64;
  float d = 0.f, n1 = 0.f, n2 = 0.f;
  for (int o = 0; o < 64; ++o) {
    float a = e1[o], c = e2[o];
    d = fmaf(a, c, d);
    n1 = fmaf(a, a, n1);
    n2 = fmaf(c, c, n2);
  }
  float nn = fmaxf(sqrtf(n1), 1e-12f) * fmaxf(sqrtf(n2), 1e-12f);
  out[b] = 0.5f * (1.f + d / nn);
}

// ---------------------------------------------------------------------------
extern "C" void kernel_launch(void* const* d_in, const int* in_sizes, int n_in,
                              void* d_out, int out_size, void* d_ws,
                              size_t ws_size, hipStream_t stream) {
  const float* CFG1 = (const float*)d_in[0];
  const float* LIT1 = (const float*)d_in[2];
  const float* SEM1 = (const float*)d_in[3];
  const float* CFG2 = (const float*)d_in[4];
  const float* LIT2 = (const float*)d_in[6];
  const float* SEM2 = (const float*)d_in[7];
  const float* WL1 = (const float*)d_in[8];
  const float* GK1 = (const float*)d_in[9];
  const float* GRK1 = (const float*)d_in[10];
  const float* GB1 = (const float*)d_in[11];
  const float* WL2 = (const float*)d_in[12];
  const float* GK2 = (const float*)d_in[13];
  const float* GRK2 = (const float*)d_in[14];
  const float* GB2 = (const float*)d_in[15];
  const float* A1W = (const float*)d_in[16];
  const float* A1B = (const float*)d_in[17];
  const float* A2W = (const float*)d_in[18];
  const float* A2B = (const float*)d_in[19];
  const float* WG = (const float*)d_in[20];
  const float* WOUT = (const float*)d_in[21];
  const float* BOUT = (const float*)d_in[22];

  float* ws = (float*)d_ws;
  float* wh = ws;            // 8388608 floats
  float* xp = wh + 8388608;  // 6291456
  unsigned int* whg = (unsigned int*)(xp + 6291456);  // 4194304 uints
  float* ah1 = (float*)(whg + 4194304);               // 65536
  float* ah2 = ah1 + 65536;                           // 65536
  float* e12 = ah2 + 65536;                           // 4096
  int* counts = (int*)(e12 + 4096);                   // 65536
  int* edges = counts + 65536;  // 4*16384*64 = 4194304

  k_data<<<1024, 64, 0, stream>>>(LIT1, SEM1, LIT2, SEM2, WL1, GK1, GB1, WL2,
                                  GK2, GB2, wh, xp);
  k_csr<<<1024, 256, 0, stream>>>(CFG1, CFG2, counts, edges);
  k_gru<<<64, 64, 0, stream>>>(xp, GRK1, GB1, GRK2, GB2, wh);
  for (int step = 0; step < 3; ++step) {
    k_whg<<<1024, 64, 0, stream>>>(wh, WG, A1W, A1B, A2W, A2B, whg, ah1, ah2);
    k_attn<<<16384, 256, 0, stream>>>(wh, whg, ah1, ah2, counts, edges);
  }
  k_tail<<<64, 256, 0, stream>>>(wh, WOUT, BOUT, e12);
  k_cos<<<1, 64, 0, stream>>>(e12, (float*)d_out);
}

// Round 7
// 783.911 us; speedup vs baseline: 1.0080x; 1.0080x over previous
//
#include <hip/hip_runtime.h>
#include <hip/hip_bf16.h>

// Problem constants
#define BB 32
#define NNODE 512
#define EE 128
#define MAXDEG 64  // fixed edge slots per row (binomial(512,.05) max ~53)

typedef float v2f __attribute__((ext_vector_type(2)));
typedef __fp16 h2 __attribute__((ext_vector_type(2)));  // matches cvt_pkrtz
__device__ __forceinline__ v2f fma2(v2f a, v2f b, v2f c) {
  return __builtin_elementwise_fma(a, b, c);
}

// Fast gates: v_rcp_f32 instead of full-precision divide (~1ulp).
__device__ __forceinline__ float sigm_fast(float x) {
  return __builtin_amdgcn_rcpf(1.0f + __expf(-x));
}
__device__ __forceinline__ float tanh_fast(float x) {
  x = fminf(20.f, fmaxf(-20.f, x));
  float t = __expf(-2.f * x);
  return (1.f - t) * __builtin_amdgcn_rcpf(1.f + t);
}

// ---------------------------------------------------------------------------
// wh[2s|2s+1][:, 0:64] = relu(LIT @ W_lit); xp = SEM @ gru_k + gru_b[0]
// grid 1024 x 64.
__global__ __launch_bounds__(64, 1) void k_data(
    const float* __restrict__ lit1, const float* __restrict__ sem1,
    const float* __restrict__ lit2, const float* __restrict__ sem2,
    const float* __restrict__ wl1, const float* __restrict__ gk1,
    const float* __restrict__ gb1, const float* __restrict__ wl2,
    const float* __restrict__ gk2, const float* __restrict__ gb2,
    float* __restrict__ wh, float* __restrict__ xp) {
  __shared__ float stage[64 * 65];
  int bid = blockIdx.x;
  int rowblk = bid >> 1, half = bid & 1;
  int grow0 = rowblk * 64;
  int side = grow0 >> 14;
  int lrow0 = grow0 & 16383;
  const float* lit = side ? lit2 : lit1;
  const float* sem = side ? sem2 : sem1;
  const float* wl = side ? wl2 : wl1;
  const float* gk = side ? gk2 : gk1;
  const float* gb = side ? gb2 : gb1;
  int tid = threadIdx.x;

  {
    const float4* lit4 = (const float4*)(lit + (size_t)lrow0 * 64);
#pragma unroll
    for (int p = 0; p < 16; ++p) {
      int s = p * 64 + tid;
      int r = s >> 4, q = s & 15;
      float4 v = lit4[r * 16 + q];
      stage[r * 65 + 4 * q + 0] = v.x;
      stage[r * 65 + 4 * q + 1] = v.y;
      stage[r * 65 + 4 * q + 2] = v.z;
      stage[r * 65 + 4 * q + 3] = v.w;
    }
    v2f acc[16];
#pragma unroll
    for (int c = 0; c < 16; ++c) acc[c] = (v2f){0.f, 0.f};
    const float4* wl4 = (const float4*)wl;  // [64][16] f4
    for (int i = 0; i < 64; ++i) {
      float rv = stage[tid * 65 + i];
      v2f rv2 = {rv, rv};
#pragma unroll
      for (int c4 = 0; c4 < 8; ++c4) {
        float4 w = wl4[i * 16 + half * 8 + c4];
        acc[2 * c4 + 0] = fma2(rv2, (v2f){w.x, w.y}, acc[2 * c4 + 0]);
        acc[2 * c4 + 1] = fma2(rv2, (v2f){w.z, w.w}, acc[2 * c4 + 1]);
      }
    }
    float4* w0 = (float4*)wh + ((size_t)(2 * side) * 16384 + lrow0 + tid) * 32;
    float4* w1 =
        (float4*)wh + ((size_t)(2 * side + 1) * 16384 + lrow0 + tid) * 32;
#pragma unroll
    for (int c4 = 0; c4 < 8; ++c4) {
      float4 o;
      o.x = fmaxf(acc[2 * c4].x, 0.f);
      o.y = fmaxf(acc[2 * c4].y, 0.f);
      o.z = fmaxf(acc[2 * c4 + 1].x, 0.f);
      o.w = fmaxf(acc[2 * c4 + 1].y, 0.f);
      w0[half * 8 + c4] = o;
      w1[half * 8 + c4] = o;
    }
  }
  {
    const float4* sem4 = (const float4*)(sem + (size_t)lrow0 * 64);
#pragma unroll
    for (int p = 0; p < 16; ++p) {
      int s = p * 64 + tid;
      int r = s >> 4, q = s & 15;
      float4 v = sem4[r * 16 + q];
      stage[r * 65 + 4 * q + 0] = v.x;
      stage[r * 65 + 4 * q + 1] = v.y;
      stage[r * 65 + 4 * q + 2] = v.z;
      stage[r * 65 + 4 * q + 3] = v.w;
    }
    v2f acc2[48];
#pragma unroll
    for (int c = 0; c < 48; ++c)
      acc2[c] = (v2f){gb[half * 96 + 2 * c], gb[half * 96 + 2 * c + 1]};
    const float4* gk4 = (const float4*)gk;  // [64][48] f4
    for (int i = 0; i < 64; ++i) {
      float rv = stage[tid * 65 + i];
      v2f rv2 = {rv, rv};
#pragma unroll
      for (int c4 = 0; c4 < 24; ++c4) {
        float4 w = gk4[i * 48 + half * 24 + c4];
        acc2[2 * c4 + 0] = fma2(rv2, (v2f){w.x, w.y}, acc2[2 * c4 + 0]);
        acc2[2 * c4 + 1] = fma2(rv2, (v2f){w.z, w.w}, acc2[2 * c4 + 1]);
      }
    }
    float4* xp4 = (float4*)xp;
    int grow = grow0 + tid;
#pragma unroll
    for (int c4 = 0; c4 < 24; ++c4) {
      float4 o;
      o.x = acc2[2 * c4].x;
      o.y = acc2[2 * c4].y;
      o.z = acc2[2 * c4 + 1].x;
      o.w = acc2[2 * c4 + 1].y;
      xp4[(size_t)grow * 48 + half * 24 + c4] = o;
    }
  }
}

// ---------------------------------------------------------------------------
// CSR/CSC build (standalone so the GRU kernel gets a full register budget).
// grid 1024 x 256.
__global__ __launch_bounds__(256, 1) void k_csr(
    const float* __restrict__ A1, const float* __restrict__ A2,
    int* __restrict__ counts, int* __restrict__ edges) {
  int bid = blockIdx.x;
  int t = threadIdx.x;
  if (bid < 512) {
    int s = bid >> 8, b = (bid >> 3) & 31, ch = bid & 7;
    const float* A = s ? A2 : A1;
    const float4* A4 = (const float4*)(A + ((size_t)b * 512 + ch * 64) * 512);
    __shared__ int crow[64];
    if (t < 64) crow[t] = 0;
    __syncthreads();
    int* efwd =
        edges + (size_t)(2 * s) * 1048576 + ((size_t)b * 512 + ch * 64) * 64;
#pragma unroll
    for (int it = 0; it < 32; ++it) {
      int idx = it * 256 + t;
      int r = idx >> 7, c4 = idx & 127;
      float4 v = A4[idx];
      float vv[4] = {v.x, v.y, v.z, v.w};
#pragma unroll
      for (int e = 0; e < 4; ++e) {
        if (vv[e] != 0.f) {
          int pos = atomicAdd(&crow[r], 1);
          if (pos < MAXDEG) efwd[r * 64 + pos] = 4 * c4 + e;
        }
      }
    }
    __syncthreads();
    if (t < 64)
      counts[(2 * s) * 16384 + b * 512 + ch * 64 + t] = min(crow[t], MAXDEG);
  } else {
    int bid2 = bid - 512;
    int s = bid2 >> 8, b = (bid2 >> 3) & 31, cch = bid2 & 7;
    const float* A = s ? A2 : A1;
    __shared__ int ccol[64];
    if (t < 64) ccol[t] = 0;
    __syncthreads();
    int lane = t & 63, rg = t >> 6;
    int c = cch * 64 + lane;
    int* erev = edges + (size_t)(2 * s + 1) * 1048576 + ((size_t)b * 512) * 64;
    const float* Ab = A + (size_t)b * 512 * 512;
    for (int it = 0; it < 128; ++it) {
      int r = it * 4 + rg;
      float a = Ab[(size_t)r * 512 + c];
      if (a != 0.f) {
        int pos = atomicAdd(&ccol[lane], 1);
        if (pos < MAXDEG) erev[(size_t)c * 64 + pos] = r;
      }
    }
    __syncthreads();
    if (t < 64)
      counts[(2 * s + 1) * 16384 + b * 512 + cch * 64 + t] =
          min(ccol[t], MAXDEG);
  }
}

// ---------------------------------------------------------------------------
// GRU scan, SINGLE-WAVE per sequence. Round-7: rounds 3/5/6 all failed to
// keep local ARRAYS in registers (VGPR_Count 140/104/96 vs ~200 needed —
// SROA left the allocas in scratch). Rule #20 fix taken to the limit: NO
// local arrays at all. 96 weight h2s and 48 x-buffer floats are individually
// NAMED scalars (SSA values, nothing for SROA to fail on).
// f16 weight columns + f16 h-broadcast (8 ds_read_b128/step, conflict-free
// same-address) + v_dot2_f32_f16, 2-way-ILP accumulators. Single-wave: no
// barriers, no shfl; sched_barrier(0) pins the hs write after the h reads.
// grid 64 x 64.
#define REP32(M)                                                          \
  M(0) M(1) M(2) M(3) M(4) M(5) M(6) M(7) M(8) M(9) M(10) M(11) M(12)    \
  M(13) M(14) M(15) M(16) M(17) M(18) M(19) M(20) M(21) M(22) M(23)      \
  M(24) M(25) M(26) M(27) M(28) M(29) M(30) M(31)

#define DECL3(K) h2 wz##K, wr##K, wv##K;

#define INIT3(K)                                                \
  {                                                             \
    const float* _r0 = rk + (size_t)(2 * K) * 192 + jj;         \
    const float* _r1 = _r0 + 192;                               \
    wz##K = __builtin_amdgcn_cvt_pkrtz(_r0[0], _r1[0]);         \
    wr##K = __builtin_amdgcn_cvt_pkrtz(_r0[64], _r1[64]);       \
    wv##K = __builtin_amdgcn_cvt_pkrtz(_r0[128], _r1[128]);     \
  }

#define DOT(W, K, S)                                                  \
  {                                                                   \
    h2 _p = __builtin_bit_cast(h2, (unsigned int)(W));                \
    _az##S = __builtin_amdgcn_fdot2(_p, wz##K, _az##S, false);        \
    _ar##S = __builtin_amdgcn_fdot2(_p, wr##K, _ar##S, false);        \
    _av##S = __builtin_amdgcn_fdot2(_p, wv##K, _av##S, false);        \
  }

#define DOTQ(HV, K0, K1, K2, K3) \
  DOT(HV.x, K0, 0) DOT(HV.y, K1, 1) DOT(HV.z, K2, 0) DOT(HV.w, K3, 1)

#define GSTEP(CXZ, CXR, CXV, t)                                       \
  do {                                                                \
    const uint4* _hb = (const uint4*)hsh;                             \
    uint4 _h0 = _hb[0], _h1 = _hb[1], _hc2 = _hb[2], _h3 = _hb[3];    \
    uint4 _h4 = _hb[4], _h5 = _hb[5], _h6 = _hb[6], _h7 = _hb[7];     \
    float _az0 = 0.f, _az1 = 0.f, _ar0 = 0.f, _ar1 = 0.f;             \
    float _av0 = 0.f, _av1 = 0.f;                                     \
    DOTQ(_h0, 0, 1, 2, 3)                                             \
    DOTQ(_h1, 4, 5, 6, 7)                                             \
    DOTQ(_hc2, 8, 9, 10, 11)                                          \
    DOTQ(_h3, 12, 13, 14, 15)                                         \
    DOTQ(_h4, 16, 17, 18, 19)                                         \
    DOTQ(_h5, 20, 21, 22, 23)                                         \
    DOTQ(_h6, 24, 25, 26, 27)                                         \
    DOTQ(_h7, 28, 29, 30, 31)                                         \
    float _z = sigm_fast((CXZ) + _az0 + _az1 + bz);                   \
    float _r = sigm_fast((CXR) + _ar0 + _ar1 + brr);                  \
    float _hh = tanh_fast((CXV) + _r * (_av0 + _av1 + bv));           \
    float _hnew = fmaf(_z, hold - _hh, _hh);                          \
    hold = _hnew;                                                     \
    __builtin_amdgcn_sched_barrier(0);                                \
    hsh[jj] = (__fp16)_hnew;                                          \
    float _rv = fmaxf(_hnew, 0.f);                                    \
    w0[(size_t)(t) * 128] = _rv;                                      \
    w1[(size_t)(t) * 128] = _rv;                                      \
  } while (0)

#define DECLB(P)                                                      \
  float P##xz0, P##xr0, P##xv0, P##xz1, P##xr1, P##xv1;               \
  float P##xz2, P##xr2, P##xv2, P##xz3, P##xr3, P##xv3;               \
  float P##xz4, P##xr4, P##xv4, P##xz5, P##xr5, P##xv5;               \
  float P##xz6, P##xr6, P##xv6, P##xz7, P##xr7, P##xv7;

#define LTRIP(P, I)                       \
  P##xz##I = _s[(I) * 192 + jj];          \
  P##xr##I = _s[(I) * 192 + 64 + jj];     \
  P##xv##I = _s[(I) * 192 + 128 + jj];

#define LOADC(P, tc)                                 \
  do {                                               \
    const float* _s = xpr + (size_t)(tc) * 1536;     \
    LTRIP(P, 0) LTRIP(P, 1) LTRIP(P, 2) LTRIP(P, 3)  \
    LTRIP(P, 4) LTRIP(P, 5) LTRIP(P, 6) LTRIP(P, 7)  \
  } while (0)

#define STEP8(P, base)                          \
  GSTEP(P##xz0, P##xr0, P##xv0, (base) + 0);    \
  GSTEP(P##xz1, P##xr1, P##xv1, (base) + 1);    \
  GSTEP(P##xz2, P##xr2, P##xv2, (base) + 2);    \
  GSTEP(P##xz3, P##xr3, P##xv3, (base) + 3);    \
  GSTEP(P##xz4, P##xr4, P##xv4, (base) + 4);    \
  GSTEP(P##xz5, P##xr5, P##xv5, (base) + 5);    \
  GSTEP(P##xz6, P##xr6, P##xv6, (base) + 6);    \
  GSTEP(P##xz7, P##xr7, P##xv7, (base) + 7);

__global__ __launch_bounds__(64, 1) void k_gru(
    const float* __restrict__ xp, const float* __restrict__ rk1,
    const float* __restrict__ b1, const float* __restrict__ rk2,
    const float* __restrict__ b2, float* __restrict__ wh) {
  int blk = blockIdx.x;
  int side = blk >> 5, b = blk & 31;
  int jj = threadIdx.x;  // output index 0..63
  const float* rk = side ? rk2 : rk1;
  const float* bbp = side ? b2 : b1;
  REP32(DECL3)
  REP32(INIT3)
  float bz = bbp[192 + jj], brr = bbp[192 + 64 + jj], bv = bbp[192 + 128 + jj];

  __shared__ alignas(16) __fp16 hsh[64];
  hsh[jj] = (__fp16)0.f;
  float hold = 0.f;

  const float* xpr = xp + (size_t)(side * 16384 + b * 512) * 192;
  float* w0 = wh + ((size_t)(2 * side) * 16384 + b * 512) * 128 + 64 + jj;
  float* w1 = wh + ((size_t)(2 * side + 1) * 16384 + b * 512) * 128 + 64 + jj;

  DECLB(A) DECLB(B)
  LOADC(A, 0);
  for (int tc2 = 0; tc2 < 32; ++tc2) {  // 64 chunks of 8 steps, paired A/B
    int tcA = 2 * tc2, tcB = 2 * tc2 + 1;
    LOADC(B, tcB);  // prefetch while computing A
    STEP8(A, tcA * 8)
    if (tcB + 1 < 64) LOADC(A, tcB + 1);  // prefetch while computing B
    STEP8(B, tcB * 8)
  }
}

// ---------------------------------------------------------------------------
// whg (PACKED BF16: uint = 2 cols) = wh @ W_g; ah1/ah2 fp32.
// grid 1024 x 64; one wave = 64 rows. XCD-swizzled (blockIdx%8 = XCD): all 8
// blocks of one (st,b) group land on the same XCD so whg stays in its L2.
__global__ __launch_bounds__(64, 1) void k_whg(
    const float* __restrict__ wh, const float* __restrict__ Wg,
    const float* __restrict__ a1w, const float* __restrict__ a1b,
    const float* __restrict__ a2w, const float* __restrict__ a2b,
    unsigned int* __restrict__ whg, float* __restrict__ ah1,
    float* __restrict__ ah2) {
  __shared__ float stage[64 * 129];
  int B = blockIdx.x;
  int xcd = B & 7, slot = B >> 3;   // slot 0..127
  int grp = xcd + 8 * (slot >> 3);  // (st,b) group 0..127
  int sub = slot & 7;               // 64-row tile within group
  int rowbase = grp * 512 + sub * 64;
  int tid = threadIdx.x;
  const float4* wh4 = (const float4*)(wh + (size_t)rowbase * 128);
#pragma unroll
  for (int p = 0; p < 32; ++p) {
    int s = p * 64 + tid;
    int r = s >> 5, q = s & 31;
    float4 v = wh4[r * 32 + q];
    stage[r * 129 + 4 * q + 0] = v.x;
    stage[r * 129 + 4 * q + 1] = v.y;
    stage[r * 129 + 4 * q + 2] = v.z;
    stage[r * 129 + 4 * q + 3] = v.w;
  }
  v2f acc[64];
#pragma unroll
  for (int c = 0; c < 64; ++c) acc[c] = (v2f){0.f, 0.f};
  float p1 = a1b[0], p2 = a2b[0];
  const float4* Wg4 = (const float4*)Wg;  // [128][32] f4
  for (int i = 0; i < 128; ++i) {
    float rv = stage[tid * 129 + i];
    v2f rv2 = {rv, rv};
    p1 = fmaf(rv, a1w[i], p1);
    p2 = fmaf(rv, a2w[i], p2);
#pragma unroll
    for (int c4 = 0; c4 < 32; ++c4) {
      float4 w = Wg4[i * 32 + c4];
      acc[2 * c4 + 0] = fma2(rv2, (v2f){w.x, w.y}, acc[2 * c4 + 0]);
      acc[2 * c4 + 1] = fma2(rv2, (v2f){w.z, w.w}, acc[2 * c4 + 1]);
    }
  }
  int grow = rowbase + tid;
  uint2* o2 = (uint2*)(whg + (size_t)grow * 64);
#pragma unroll
  for (int c4 = 0; c4 < 32; c4 += 2) {
    __hip_bfloat162 A =
        __float22bfloat162_rn(make_float2(acc[c4].x, acc[c4].y));
    __hip_bfloat162 Bv =
        __float22bfloat162_rn(make_float2(acc[c4 + 1].x, acc[c4 + 1].y));
    uint2 pk;
    pk.x = *(unsigned int*)&A;
    pk.y = *(unsigned int*)&Bv;
    o2[c4 >> 1] = pk;
  }
  ah1[grow] = p1;
  ah2[grow] = p2;
}

// ---------------------------------------------------------------------------
// Per-row edge softmax + aggregate + elu. One wave per row, 4 rows per block.
// Lane-parallel setup; shfl-broadcast gather; whg is PACKED BF16 so each lane
// reads ONE 4B uint (2 cols) per edge — half the loads/bytes of fp32.
// XCD-swizzled to match k_whg. grid 16384 x 256.
__global__ __launch_bounds__(256, 1) void k_attn(
    float* __restrict__ wh, const unsigned int* __restrict__ whg,
    const float* __restrict__ ah1, const float* __restrict__ ah2,
    const int* __restrict__ counts, const int* __restrict__ edges) {
  int B = blockIdx.x;
  int xcd = B & 7, slot = B >> 3;   // slot 0..2047
  int grp = xcd + 8 * (slot >> 7);  // group 0..127
  int sub = slot & 127;             // 0..127 (4 rows each)
  int row = grp * 512 + sub * 4 + (threadIdx.x >> 6);
  int lane = threadIdx.x & 63;
  int st = row >> 14;
  int loc = row & 16383;
  int base = row & ~511;
  int cnt = counts[row];
  const int* ed = edges + (size_t)st * 1048576 + (size_t)loc * 64;
  int jk = lane < cnt ? ed[lane] : 0;
  float a1v = ah1[row];
  float e = a1v + ah2[base + jk];
  e = e >= 0.f ? e : 0.2f * e;  // leaky_relu 0.2
  float w = lane < cnt ? __expf(e) : 0.f;
  float lsum = w;
#pragma unroll
  for (int off = 32; off; off >>= 1) lsum += __shfl_xor(lsum, off, 64);
  float inv = cnt > 0 ? 1.0f / lsum : 0.f;
  const unsigned int* wgb = whg + (size_t)base * 64;
  v2f a0 = {0.f, 0.f}, a1 = {0.f, 0.f}, a2 = {0.f, 0.f}, a3 = {0.f, 0.f};
  int k = 0;
  for (; k + 4 <= cnt; k += 4) {
    float w0 = __shfl(w, k, 64), w1 = __shfl(w, k + 1, 64);
    float w2 = __shfl(w, k + 2, 64), w3 = __shfl(w, k + 3, 64);
    int j0 = __shfl(jk, k, 64), j1 = __shfl(jk, k + 1, 64);
    int j2 = __shfl(jk, k + 2, 64), j3 = __shfl(jk, k + 3, 64);
    unsigned int d0 = wgb[(size_t)j0 * 64 + lane];
    unsigned int d1 = wgb[(size_t)j1 * 64 + lane];
    unsigned int d2 = wgb[(size_t)j2 * 64 + lane];
    unsigned int d3 = wgb[(size_t)j3 * 64 + lane];
    v2f v0 = {__uint_as_float(d0 << 16), __uint_as_float(d0 & 0xffff0000u)};
    v2f v1 = {__uint_as_float(d1 << 16), __uint_as_float(d1 & 0xffff0000u)};
    v2f v2 = {__uint_as_float(d2 << 16), __uint_as_float(d2 & 0xffff0000u)};
    v2f v3 = {__uint_as_float(d3 << 16), __uint_as_float(d3 & 0xffff0000u)};
    a0 = fma2((v2f){w0, w0}, v0, a0);
    a1 = fma2((v2f){w1, w1}, v1, a1);
    a2 = fma2((v2f){w2, w2}, v2, a2);
    a3 = fma2((v2f){w3, w3}, v3, a3);
  }
  for (; k < cnt; ++k) {
    float w0 = __shfl(w, k, 64);
    int j0 = __shfl(jk, k, 64);
    unsigned int d0 = wgb[(size_t)j0 * 64 + lane];
    v2f v0 = {__uint_as_float(d0 << 16), __uint_as_float(d0 & 0xffff0000u)};
    a0 = fma2((v2f){w0, w0}, v0, a0);
  }
  v2f acc = (a0 + a1) + (a2 + a3);
  // lane covers cols 2*lane, 2*lane+1
  float2* wr2 = (float2*)(wh + (size_t)row * 128);
  float2 old = wr2[lane];
  float o0 = old.x + acc.x * inv;
  float o1 = old.y + acc.y * inv;
  o0 = o0 > 0.f ? o0 : __expf(o0) - 1.f;  // elu
  o1 = o1 > 0.f ? o1 : __expf(o1) - 1.f;
  wr2[lane] = make_float2(o0, o1);
}

// ---------------------------------------------------------------------------
// Fused node-sum + output projection. grid 64 x 256. Block = (side,b).
__global__ __launch_bounds__(256, 1) void k_tail(const float* __restrict__ wh,
                                                 const float* __restrict__ Wout,
                                                 const float* __restrict__ bout,
                                                 float* __restrict__ e12) {
  int sb = blockIdx.x;
  int side = sb >> 5, b = sb & 31;
  int t = threadIdx.x;
  int c = t & 127, half = t >> 7;
  __shared__ float part[2][128];
  __shared__ float mid[128];
  size_t s0 = ((size_t)(2 * side) * 16384 + b * 512) * 128;
  size_t s1 = ((size_t)(2 * side + 1) * 16384 + b * 512) * 128;
  float sum = 0.f;
  int r0 = half * 256;
  for (int r = r0; r < r0 + 256; ++r) {
    sum += wh[s0 + (size_t)r * 128 + c] + wh[s1 + (size_t)r * 128 + c];
  }
  part[half][c] = sum;
  __syncthreads();
  if (t < 128) mid[t] = part[0][t] + part[1][t];
  __syncthreads();
  if (t < 64) {
    float acc = bout[t];
    for (int k2 = 0; k2 < 128; ++k2) acc = fmaf(mid[k2], Wout[k2 * 64 + t], acc);
    e12[sb * 64 + t] = acc;
  }
}

__global__ void k_cos(const float* __restrict__ e12, float* __restrict__ out) {
  int b = threadIdx.x;
  if (b >= 32) return;
  const float* e1 = e12 + b * 64;
  const float* e2 = e12 + 2048 + b * 64;
  float d = 0.f, n1 = 0.f, n2 = 0.f;
  for (int o = 0; o < 64; ++o) {
    float a = e1[o], c = e2[o];
    d = fmaf(a, c, d);
    n1 = fmaf(a, a, n1);
    n2 = fmaf(c, c, n2);
  }
  float nn = fmaxf(sqrtf(n1), 1e-12f) * fmaxf(sqrtf(n2), 1e-12f);
  out[b] = 0.5f * (1.f + d / nn);
}

// ---------------------------------------------------------------------------
extern "C" void kernel_launch(void* const* d_in, const int* in_sizes, int n_in,
                              void* d_out, int out_size, void* d_ws,
                              size_t ws_size, hipStream_t stream) {
  const float* CFG1 = (const float*)d_in[0];
  const float* LIT1 = (const float*)d_in[2];
  const float* SEM1 = (const float*)d_in[3];
  const float* CFG2 = (const float*)d_in[4];
  const float* LIT2 = (const float*)d_in[6];
  const float* SEM2 = (const float*)d_in[7];
  const float* WL1 = (const float*)d_in[8];
  const float* GK1 = (const float*)d_in[9];
  const float* GRK1 = (const float*)d_in[10];
  const float* GB1 = (const float*)d_in[11];
  const float* WL2 = (const float*)d_in[12];
  const float* GK2 = (const float*)d_in[13];
  const float* GRK2 = (const float*)d_in[14];
  const float* GB2 = (const float*)d_in[15];
  const float* A1W = (const float*)d_in[16];
  const float* A1B = (const float*)d_in[17];
  const float* A2W = (const float*)d_in[18];
  const float* A2B = (const float*)d_in[19];
  const float* WG = (const float*)d_in[20];
  const float* WOUT = (const float*)d_in[21];
  const float* BOUT = (const float*)d_in[22];

  float* ws = (float*)d_ws;
  float* wh = ws;            // 8388608 floats
  float* xp = wh + 8388608;  // 6291456
  unsigned int* whg = (unsigned int*)(xp + 6291456);  // 4194304 uints
  float* ah1 = (float*)(whg + 4194304);               // 65536
  float* ah2 = ah1 + 65536;                           // 65536
  float* e12 = ah2 + 65536;                           // 4096
  int* counts = (int*)(e12 + 4096);                   // 65536
  int* edges = counts + 65536;  // 4*16384*64 = 4194304

  k_data<<<1024, 64, 0, stream>>>(LIT1, SEM1, LIT2, SEM2, WL1, GK1, GB1, WL2,
                                  GK2, GB2, wh, xp);
  k_csr<<<1024, 256, 0, stream>>>(CFG1, CFG2, counts, edges);
  k_gru<<<64, 64, 0, stream>>>(xp, GRK1, GB1, GRK2, GB2, wh);
  for (int step = 0; step < 3; ++step) {
    k_whg<<<1024, 64, 0, stream>>>(wh, WG, A1W, A1B, A2W, A2B, whg, ah1, ah2);
    k_attn<<<16384, 256, 0, stream>>>(wh, whg, ah1, ah2, counts, edges);
  }
  k_tail<<<64, 256, 0, stream>>>(wh, WOUT, BOUT, e12);
  k_cos<<<1, 64, 0, stream>>>(e12, (float*)d_out);
}

// Round 8
// 782.360 us; speedup vs baseline: 1.0100x; 1.0020x over previous
//
#include <hip/hip_runtime.h>
#include <hip/hip_bf16.h>

// Problem constants
#define BB 32
#define NNODE 512
#define EE 128
#define MAXDEG 64  // fixed edge slots per row (binomial(512,.05) max ~53)

typedef float v2f __attribute__((ext_vector_type(2)));
typedef __fp16 h2 __attribute__((ext_vector_type(2)));  // matches cvt_pkrtz
__device__ __forceinline__ v2f fma2(v2f a, v2f b, v2f c) {
  return __builtin_elementwise_fma(a, b, c);
}

// Fast gates: v_rcp_f32 instead of full-precision divide (~1ulp).
__device__ __forceinline__ float sigm_fast(float x) {
  return __builtin_amdgcn_rcpf(1.0f + __expf(-x));
}
__device__ __forceinline__ float tanh_fast(float x) {
  x = fminf(20.f, fmaxf(-20.f, x));
  float t = __expf(-2.f * x);
  return (1.f - t) * __builtin_amdgcn_rcpf(1.f + t);
}

// ---------------------------------------------------------------------------
// wh[2s|2s+1][:, 0:64] = relu(LIT @ W_lit); xp = SEM @ gru_k + gru_b[0]
// grid 1024 x 64.
__global__ __launch_bounds__(64, 1) void k_data(
    const float* __restrict__ lit1, const float* __restrict__ sem1,
    const float* __restrict__ lit2, const float* __restrict__ sem2,
    const float* __restrict__ wl1, const float* __restrict__ gk1,
    const float* __restrict__ gb1, const float* __restrict__ wl2,
    const float* __restrict__ gk2, const float* __restrict__ gb2,
    float* __restrict__ wh, float* __restrict__ xp) {
  __shared__ float stage[64 * 65];
  int bid = blockIdx.x;
  int rowblk = bid >> 1, half = bid & 1;
  int grow0 = rowblk * 64;
  int side = grow0 >> 14;
  int lrow0 = grow0 & 16383;
  const float* lit = side ? lit2 : lit1;
  const float* sem = side ? sem2 : sem1;
  const float* wl = side ? wl2 : wl1;
  const float* gk = side ? gk2 : gk1;
  const float* gb = side ? gb2 : gb1;
  int tid = threadIdx.x;

  {
    const float4* lit4 = (const float4*)(lit + (size_t)lrow0 * 64);
#pragma unroll
    for (int p = 0; p < 16; ++p) {
      int s = p * 64 + tid;
      int r = s >> 4, q = s & 15;
      float4 v = lit4[r * 16 + q];
      stage[r * 65 + 4 * q + 0] = v.x;
      stage[r * 65 + 4 * q + 1] = v.y;
      stage[r * 65 + 4 * q + 2] = v.z;
      stage[r * 65 + 4 * q + 3] = v.w;
    }
    v2f acc[16];
#pragma unroll
    for (int c = 0; c < 16; ++c) acc[c] = (v2f){0.f, 0.f};
    const float4* wl4 = (const float4*)wl;  // [64][16] f4
    for (int i = 0; i < 64; ++i) {
      float rv = stage[tid * 65 + i];
      v2f rv2 = {rv, rv};
#pragma unroll
      for (int c4 = 0; c4 < 8; ++c4) {
        float4 w = wl4[i * 16 + half * 8 + c4];
        acc[2 * c4 + 0] = fma2(rv2, (v2f){w.x, w.y}, acc[2 * c4 + 0]);
        acc[2 * c4 + 1] = fma2(rv2, (v2f){w.z, w.w}, acc[2 * c4 + 1]);
      }
    }
    float4* w0 = (float4*)wh + ((size_t)(2 * side) * 16384 + lrow0 + tid) * 32;
    float4* w1 =
        (float4*)wh + ((size_t)(2 * side + 1) * 16384 + lrow0 + tid) * 32;
#pragma unroll
    for (int c4 = 0; c4 < 8; ++c4) {
      float4 o;
      o.x = fmaxf(acc[2 * c4].x, 0.f);
      o.y = fmaxf(acc[2 * c4].y, 0.f);
      o.z = fmaxf(acc[2 * c4 + 1].x, 0.f);
      o.w = fmaxf(acc[2 * c4 + 1].y, 0.f);
      w0[half * 8 + c4] = o;
      w1[half * 8 + c4] = o;
    }
  }
  {
    const float4* sem4 = (const float4*)(sem + (size_t)lrow0 * 64);
#pragma unroll
    for (int p = 0; p < 16; ++p) {
      int s = p * 64 + tid;
      int r = s >> 4, q = s & 15;
      float4 v = sem4[r * 16 + q];
      stage[r * 65 + 4 * q + 0] = v.x;
      stage[r * 65 + 4 * q + 1] = v.y;
      stage[r * 65 + 4 * q + 2] = v.z;
      stage[r * 65 + 4 * q + 3] = v.w;
    }
    v2f acc2[48];
#pragma unroll
    for (int c = 0; c < 48; ++c)
      acc2[c] = (v2f){gb[half * 96 + 2 * c], gb[half * 96 + 2 * c + 1]};
    const float4* gk4 = (const float4*)gk;  // [64][48] f4
    for (int i = 0; i < 64; ++i) {
      float rv = stage[tid * 65 + i];
      v2f rv2 = {rv, rv};
#pragma unroll
      for (int c4 = 0; c4 < 24; ++c4) {
        float4 w = gk4[i * 48 + half * 24 + c4];
        acc2[2 * c4 + 0] = fma2(rv2, (v2f){w.x, w.y}, acc2[2 * c4 + 0]);
        acc2[2 * c4 + 1] = fma2(rv2, (v2f){w.z, w.w}, acc2[2 * c4 + 1]);
      }
    }
    float4* xp4 = (float4*)xp;
    int grow = grow0 + tid;
#pragma unroll
    for (int c4 = 0; c4 < 24; ++c4) {
      float4 o;
      o.x = acc2[2 * c4].x;
      o.y = acc2[2 * c4].y;
      o.z = acc2[2 * c4 + 1].x;
      o.w = acc2[2 * c4 + 1].y;
      xp4[(size_t)grow * 48 + half * 24 + c4] = o;
    }
  }
}

// ---------------------------------------------------------------------------
// CSR/CSC build (standalone so the GRU kernel gets a full register budget).
// grid 1024 x 256.
__global__ __launch_bounds__(256, 1) void k_csr(
    const float* __restrict__ A1, const float* __restrict__ A2,
    int* __restrict__ counts, int* __restrict__ edges) {
  int bid = blockIdx.x;
  int t = threadIdx.x;
  if (bid < 512) {
    int s = bid >> 8, b = (bid >> 3) & 31, ch = bid & 7;
    const float* A = s ? A2 : A1;
    const float4* A4 = (const float4*)(A + ((size_t)b * 512 + ch * 64) * 512);
    __shared__ int crow[64];
    if (t < 64) crow[t] = 0;
    __syncthreads();
    int* efwd =
        edges + (size_t)(2 * s) * 1048576 + ((size_t)b * 512 + ch * 64) * 64;
#pragma unroll
    for (int it = 0; it < 32; ++it) {
      int idx = it * 256 + t;
      int r = idx >> 7, c4 = idx & 127;
      float4 v = A4[idx];
      float vv[4] = {v.x, v.y, v.z, v.w};
#pragma unroll
      for (int e = 0; e < 4; ++e) {
        if (vv[e] != 0.f) {
          int pos = atomicAdd(&crow[r], 1);
          if (pos < MAXDEG) efwd[r * 64 + pos] = 4 * c4 + e;
        }
      }
    }
    __syncthreads();
    if (t < 64)
      counts[(2 * s) * 16384 + b * 512 + ch * 64 + t] = min(crow[t], MAXDEG);
  } else {
    int bid2 = bid - 512;
    int s = bid2 >> 8, b = (bid2 >> 3) & 31, cch = bid2 & 7;
    const float* A = s ? A2 : A1;
    __shared__ int ccol[64];
    if (t < 64) ccol[t] = 0;
    __syncthreads();
    int lane = t & 63, rg = t >> 6;
    int c = cch * 64 + lane;
    int* erev = edges + (size_t)(2 * s + 1) * 1048576 + ((size_t)b * 512) * 64;
    const float* Ab = A + (size_t)b * 512 * 512;
    for (int it = 0; it < 128; ++it) {
      int r = it * 4 + rg;
      float a = Ab[(size_t)r * 512 + c];
      if (a != 0.f) {
        int pos = atomicAdd(&ccol[lane], 1);
        if (pos < MAXDEG) erev[(size_t)c * 64 + pos] = r;
      }
    }
    __syncthreads();
    if (t < 64)
      counts[(2 * s + 1) * 16384 + b * 512 + cch * 64 + t] =
          min(ccol[t], MAXDEG);
  }
}

// ---------------------------------------------------------------------------
// GRU scan, SINGLE-WAVE per sequence. Round-8: rounds 3/5/6/7 all ended at
// VGPR_Count ~100 — NOT an SROA/alloca failure (round 7 had no arrays). The
// scheduler REMATERIALIZES the loop-invariant weight loads (readonly global
// + cvt) into the loop instead of keeping ~100 registers live, re-fetching
// all 96 weights from L2 every step (~760 cy/step, VALUBusy 4%). Fix: pin
// each weight through an opaque inline-asm pass-through after the prologue —
// asm outputs cannot be remat'd, forcing register residency (512-VGPR budget
// at launch_bounds(64,1) absorbs ~200 live values without spill).
// grid 64 x 64.
#define REP32(M)                                                          \
  M(0) M(1) M(2) M(3) M(4) M(5) M(6) M(7) M(8) M(9) M(10) M(11) M(12)    \
  M(13) M(14) M(15) M(16) M(17) M(18) M(19) M(20) M(21) M(22) M(23)      \
  M(24) M(25) M(26) M(27) M(28) M(29) M(30) M(31)

#define DECL3(K) h2 wz##K, wr##K, wv##K;

#define INIT3(K)                                                \
  {                                                             \
    const float* _r0 = rk + (size_t)(2 * K) * 192 + jj;         \
    const float* _r1 = _r0 + 192;                               \
    wz##K = __builtin_amdgcn_cvt_pkrtz(_r0[0], _r1[0]);         \
    wr##K = __builtin_amdgcn_cvt_pkrtz(_r0[64], _r1[64]);       \
    wv##K = __builtin_amdgcn_cvt_pkrtz(_r0[128], _r1[128]);     \
  }

// Anti-remat pin: route each weight through opaque asm so the scheduler
// cannot sink/rematerialize the producing load into the step loop.
#define PIN3(K)                                                       \
  {                                                                   \
    unsigned int _uz = __builtin_bit_cast(unsigned int, wz##K);       \
    unsigned int _ur = __builtin_bit_cast(unsigned int, wr##K);       \
    unsigned int _uv = __builtin_bit_cast(unsigned int, wv##K);       \
    asm volatile("" : "+v"(_uz), "+v"(_ur), "+v"(_uv));               \
    wz##K = __builtin_bit_cast(h2, _uz);                              \
    wr##K = __builtin_bit_cast(h2, _ur);                              \
    wv##K = __builtin_bit_cast(h2, _uv);                              \
  }

#define DOT(W, K, S)                                                  \
  {                                                                   \
    h2 _p = __builtin_bit_cast(h2, (unsigned int)(W));                \
    _az##S = __builtin_amdgcn_fdot2(_p, wz##K, _az##S, false);        \
    _ar##S = __builtin_amdgcn_fdot2(_p, wr##K, _ar##S, false);        \
    _av##S = __builtin_amdgcn_fdot2(_p, wv##K, _av##S, false);        \
  }

#define DOTQ(HV, K0, K1, K2, K3) \
  DOT(HV.x, K0, 0) DOT(HV.y, K1, 1) DOT(HV.z, K2, 0) DOT(HV.w, K3, 1)

#define GSTEP(CXZ, CXR, CXV, t)                                       \
  do {                                                                \
    const uint4* _hb = (const uint4*)hsh;                             \
    uint4 _h0 = _hb[0], _h1 = _hb[1], _hc2 = _hb[2], _h3 = _hb[3];    \
    uint4 _h4 = _hb[4], _h5 = _hb[5], _h6 = _hb[6], _h7 = _hb[7];     \
    float _az0 = 0.f, _az1 = 0.f, _ar0 = 0.f, _ar1 = 0.f;             \
    float _av0 = 0.f, _av1 = 0.f;                                     \
    DOTQ(_h0, 0, 1, 2, 3)                                             \
    DOTQ(_h1, 4, 5, 6, 7)                                             \
    DOTQ(_hc2, 8, 9, 10, 11)                                          \
    DOTQ(_h3, 12, 13, 14, 15)                                         \
    DOTQ(_h4, 16, 17, 18, 19)                                         \
    DOTQ(_h5, 20, 21, 22, 23)                                         \
    DOTQ(_h6, 24, 25, 26, 27)                                         \
    DOTQ(_h7, 28, 29, 30, 31)                                         \
    float _z = sigm_fast((CXZ) + _az0 + _az1 + bz);                   \
    float _r = sigm_fast((CXR) + _ar0 + _ar1 + brr);                  \
    float _hh = tanh_fast((CXV) + _r * (_av0 + _av1 + bv));           \
    float _hnew = fmaf(_z, hold - _hh, _hh);                          \
    hold = _hnew;                                                     \
    __builtin_amdgcn_sched_barrier(0);                                \
    hsh[jj] = (__fp16)_hnew;                                          \
    float _rv = fmaxf(_hnew, 0.f);                                    \
    w0[(size_t)(t) * 128] = _rv;                                      \
    w1[(size_t)(t) * 128] = _rv;                                      \
  } while (0)

#define DECLB(P)                                                      \
  float P##xz0, P##xr0, P##xv0, P##xz1, P##xr1, P##xv1;               \
  float P##xz2, P##xr2, P##xv2, P##xz3, P##xr3, P##xv3;               \
  float P##xz4, P##xr4, P##xv4, P##xz5, P##xr5, P##xv5;               \
  float P##xz6, P##xr6, P##xv6, P##xz7, P##xr7, P##xv7;

#define LTRIP(P, I)                       \
  P##xz##I = _s[(I) * 192 + jj];          \
  P##xr##I = _s[(I) * 192 + 64 + jj];     \
  P##xv##I = _s[(I) * 192 + 128 + jj];

#define LOADC(P, tc)                                 \
  do {                                               \
    const float* _s = xpr + (size_t)(tc) * 1536;     \
    LTRIP(P, 0) LTRIP(P, 1) LTRIP(P, 2) LTRIP(P, 3)  \
    LTRIP(P, 4) LTRIP(P, 5) LTRIP(P, 6) LTRIP(P, 7)  \
  } while (0)

#define STEP8(P, base)                          \
  GSTEP(P##xz0, P##xr0, P##xv0, (base) + 0);    \
  GSTEP(P##xz1, P##xr1, P##xv1, (base) + 1);    \
  GSTEP(P##xz2, P##xr2, P##xv2, (base) + 2);    \
  GSTEP(P##xz3, P##xr3, P##xv3, (base) + 3);    \
  GSTEP(P##xz4, P##xr4, P##xv4, (base) + 4);    \
  GSTEP(P##xz5, P##xr5, P##xv5, (base) + 5);    \
  GSTEP(P##xz6, P##xr6, P##xv6, (base) + 6);    \
  GSTEP(P##xz7, P##xr7, P##xv7, (base) + 7);

__global__ __launch_bounds__(64, 1) void k_gru(
    const float* __restrict__ xp, const float* __restrict__ rk1,
    const float* __restrict__ b1, const float* __restrict__ rk2,
    const float* __restrict__ b2, float* __restrict__ wh) {
  int blk = blockIdx.x;
  int side = blk >> 5, b = blk & 31;
  int jj = threadIdx.x;  // output index 0..63
  const float* rk = side ? rk2 : rk1;
  const float* bbp = side ? b2 : b1;
  REP32(DECL3)
  REP32(INIT3)
  REP32(PIN3)
  float bz = bbp[192 + jj], brr = bbp[192 + 64 + jj], bv = bbp[192 + 128 + jj];

  __shared__ alignas(16) __fp16 hsh[64];
  hsh[jj] = (__fp16)0.f;
  float hold = 0.f;

  const float* xpr = xp + (size_t)(side * 16384 + b * 512) * 192;
  float* w0 = wh + ((size_t)(2 * side) * 16384 + b * 512) * 128 + 64 + jj;
  float* w1 = wh + ((size_t)(2 * side + 1) * 16384 + b * 512) * 128 + 64 + jj;

  DECLB(A) DECLB(B)
  LOADC(A, 0);
  for (int tc2 = 0; tc2 < 32; ++tc2) {  // 64 chunks of 8 steps, paired A/B
    int tcA = 2 * tc2, tcB = 2 * tc2 + 1;
    LOADC(B, tcB);  // prefetch while computing A
    STEP8(A, tcA * 8)
    if (tcB + 1 < 64) LOADC(A, tcB + 1);  // prefetch while computing B
    STEP8(B, tcB * 8)
  }
}

// ---------------------------------------------------------------------------
// whg (PACKED BF16: uint = 2 cols) = wh @ W_g; ah1/ah2 fp32.
// grid 1024 x 64; one wave = 64 rows. XCD-swizzled (blockIdx%8 = XCD): all 8
// blocks of one (st,b) group land on the same XCD so whg stays in its L2.
__global__ __launch_bounds__(64, 1) void k_whg(
    const float* __restrict__ wh, const float* __restrict__ Wg,
    const float* __restrict__ a1w, const float* __restrict__ a1b,
    const float* __restrict__ a2w, const float* __restrict__ a2b,
    unsigned int* __restrict__ whg, float* __restrict__ ah1,
    float* __restrict__ ah2) {
  __shared__ float stage[64 * 129];
  int B = blockIdx.x;
  int xcd = B & 7, slot = B >> 3;   // slot 0..127
  int grp = xcd + 8 * (slot >> 3);  // (st,b) group 0..127
  int sub = slot & 7;               // 64-row tile within group
  int rowbase = grp * 512 + sub * 64;
  int tid = threadIdx.x;
  const float4* wh4 = (const float4*)(wh + (size_t)rowbase * 128);
#pragma unroll
  for (int p = 0; p < 32; ++p) {
    int s = p * 64 + tid;
    int r = s >> 5, q = s & 31;
    float4 v = wh4[r * 32 + q];
    stage[r * 129 + 4 * q + 0] = v.x;
    stage[r * 129 + 4 * q + 1] = v.y;
    stage[r * 129 + 4 * q + 2] = v.z;
    stage[r * 129 + 4 * q + 3] = v.w;
  }
  v2f acc[64];
#pragma unroll
  for (int c = 0; c < 64; ++c) acc[c] = (v2f){0.f, 0.f};
  float p1 = a1b[0], p2 = a2b[0];
  const float4* Wg4 = (const float4*)Wg;  // [128][32] f4
  for (int i = 0; i < 128; ++i) {
    float rv = stage[tid * 129 + i];
    v2f rv2 = {rv, rv};
    p1 = fmaf(rv, a1w[i], p1);
    p2 = fmaf(rv, a2w[i], p2);
#pragma unroll
    for (int c4 = 0; c4 < 32; ++c4) {
      float4 w = Wg4[i * 32 + c4];
      acc[2 * c4 + 0] = fma2(rv2, (v2f){w.x, w.y}, acc[2 * c4 + 0]);
      acc[2 * c4 + 1] = fma2(rv2, (v2f){w.z, w.w}, acc[2 * c4 + 1]);
    }
  }
  int grow = rowbase + tid;
  uint2* o2 = (uint2*)(whg + (size_t)grow * 64);
#pragma unroll
  for (int c4 = 0; c4 < 32; c4 += 2) {
    __hip_bfloat162 A =
        __float22bfloat162_rn(make_float2(acc[c4].x, acc[c4].y));
    __hip_bfloat162 Bv =
        __float22bfloat162_rn(make_float2(acc[c4 + 1].x, acc[c4 + 1].y));
    uint2 pk;
    pk.x = *(unsigned int*)&A;
    pk.y = *(unsigned int*)&Bv;
    o2[c4 >> 1] = pk;
  }
  ah1[grow] = p1;
  ah2[grow] = p2;
}

// ---------------------------------------------------------------------------
// Per-row edge softmax + aggregate + elu. One wave per row, 4 rows per block.
// Lane-parallel setup; shfl-broadcast gather; whg is PACKED BF16 so each lane
// reads ONE 4B uint (2 cols) per edge — half the loads/bytes of fp32.
// XCD-swizzled to match k_whg. grid 16384 x 256.
__global__ __launch_bounds__(256, 1) void k_attn(
    float* __restrict__ wh, const unsigned int* __restrict__ whg,
    const float* __restrict__ ah1, const float* __restrict__ ah2,
    const int* __restrict__ counts, const int* __restrict__ edges) {
  int B = blockIdx.x;
  int xcd = B & 7, slot = B >> 3;   // slot 0..2047
  int grp = xcd + 8 * (slot >> 7);  // group 0..127
  int sub = slot & 127;             // 0..127 (4 rows each)
  int row = grp * 512 + sub * 4 + (threadIdx.x >> 6);
  int lane = threadIdx.x & 63;
  int st = row >> 14;
  int loc = row & 16383;
  int base = row & ~511;
  int cnt = counts[row];
  const int* ed = edges + (size_t)st * 1048576 + (size_t)loc * 64;
  int jk = lane < cnt ? ed[lane] : 0;
  float a1v = ah1[row];
  float e = a1v + ah2[base + jk];
  e = e >= 0.f ? e : 0.2f * e;  // leaky_relu 0.2
  float w = lane < cnt ? __expf(e) : 0.f;
  float lsum = w;
#pragma unroll
  for (int off = 32; off; off >>= 1) lsum += __shfl_xor(lsum, off, 64);
  float inv = cnt > 0 ? 1.0f / lsum : 0.f;
  const unsigned int* wgb = whg + (size_t)base * 64;
  v2f a0 = {0.f, 0.f}, a1 = {0.f, 0.f}, a2 = {0.f, 0.f}, a3 = {0.f, 0.f};
  int k = 0;
  for (; k + 4 <= cnt; k += 4) {
    float w0 = __shfl(w, k, 64), w1 = __shfl(w, k + 1, 64);
    float w2 = __shfl(w, k + 2, 64), w3 = __shfl(w, k + 3, 64);
    int j0 = __shfl(jk, k, 64), j1 = __shfl(jk, k + 1, 64);
    int j2 = __shfl(jk, k + 2, 64), j3 = __shfl(jk, k + 3, 64);
    unsigned int d0 = wgb[(size_t)j0 * 64 + lane];
    unsigned int d1 = wgb[(size_t)j1 * 64 + lane];
    unsigned int d2 = wgb[(size_t)j2 * 64 + lane];
    unsigned int d3 = wgb[(size_t)j3 * 64 + lane];
    v2f v0 = {__uint_as_float(d0 << 16), __uint_as_float(d0 & 0xffff0000u)};
    v2f v1 = {__uint_as_float(d1 << 16), __uint_as_float(d1 & 0xffff0000u)};
    v2f v2 = {__uint_as_float(d2 << 16), __uint_as_float(d2 & 0xffff0000u)};
    v2f v3 = {__uint_as_float(d3 << 16), __uint_as_float(d3 & 0xffff0000u)};
    a0 = fma2((v2f){w0, w0}, v0, a0);
    a1 = fma2((v2f){w1, w1}, v1, a1);
    a2 = fma2((v2f){w2, w2}, v2, a2);
    a3 = fma2((v2f){w3, w3}, v3, a3);
  }
  for (; k < cnt; ++k) {
    float w0 = __shfl(w, k, 64);
    int j0 = __shfl(jk, k, 64);
    unsigned int d0 = wgb[(size_t)j0 * 64 + lane];
    v2f v0 = {__uint_as_float(d0 << 16), __uint_as_float(d0 & 0xffff0000u)};
    a0 = fma2((v2f){w0, w0}, v0, a0);
  }
  v2f acc = (a0 + a1) + (a2 + a3);
  // lane covers cols 2*lane, 2*lane+1
  float2* wr2 = (float2*)(wh + (size_t)row * 128);
  float2 old = wr2[lane];
  float o0 = old.x + acc.x * inv;
  float o1 = old.y + acc.y * inv;
  o0 = o0 > 0.f ? o0 : __expf(o0) - 1.f;  // elu
  o1 = o1 > 0.f ? o1 : __expf(o1) - 1.f;
  wr2[lane] = make_float2(o0, o1);
}

// ---------------------------------------------------------------------------
// Fused node-sum + output projection. grid 64 x 256. Block = (side,b).
__global__ __launch_bounds__(256, 1) void k_tail(const float* __restrict__ wh,
                                                 const float* __restrict__ Wout,
                                                 const float* __restrict__ bout,
                                                 float* __restrict__ e12) {
  int sb = blockIdx.x;
  int side = sb >> 5, b = sb & 31;
  int t = threadIdx.x;
  int c = t & 127, half = t >> 7;
  __shared__ float part[2][128];
  __shared__ float mid[128];
  size_t s0 = ((size_t)(2 * side) * 16384 + b * 512) * 128;
  size_t s1 = ((size_t)(2 * side + 1) * 16384 + b * 512) * 128;
  float sum = 0.f;
  int r0 = half * 256;
  for (int r = r0; r < r0 + 256; ++r) {
    sum += wh[s0 + (size_t)r * 128 + c] + wh[s1 + (size_t)r * 128 + c];
  }
  part[half][c] = sum;
  __syncthreads();
  if (t < 128) mid[t] = part[0][t] + part[1][t];
  __syncthreads();
  if (t < 64) {
    float acc = bout[t];
    for (int k2 = 0; k2 < 128; ++k2) acc = fmaf(mid[k2], Wout[k2 * 64 + t], acc);
    e12[sb * 64 + t] = acc;
  }
}

__global__ void k_cos(const float* __restrict__ e12, float* __restrict__ out) {
  int b = threadIdx.x;
  if (b >= 32) return;
  const float* e1 = e12 + b * 64;
  const float* e2 = e12 + 2048 + b * 64;
  float d = 0.f, n1 = 0.f, n2 = 0.f;
  for (int o = 0; o < 64; ++o) {
    float a = e1[o], c = e2[o];
    d = fmaf(a, c, d);
    n1 = fmaf(a, a, n1);
    n2 = fmaf(c, c, n2);
  }
  float nn = fmaxf(sqrtf(n1), 1e-12f) * fmaxf(sqrtf(n2), 1e-12f);
  out[b] = 0.5f * (1.f + d / nn);
}

// ---------------------------------------------------------------------------
extern "C" void kernel_launch(void* const* d_in, const int* in_sizes, int n_in,
                              void* d_out, int out_size, void* d_ws,
                              size_t ws_size, hipStream_t stream) {
  const float* CFG1 = (const float*)d_in[0];
  const float* LIT1 = (const float*)d_in[2];
  const float* SEM1 = (const float*)d_in[3];
  const float* CFG2 = (const float*)d_in[4];
  const float* LIT2 = (const float*)d_in[6];
  const float* SEM2 = (const float*)d_in[7];
  const float* WL1 = (const float*)d_in[8];
  const float* GK1 = (const float*)d_in[9];
  const float* GRK1 = (const float*)d_in[10];
  const float* GB1 = (const float*)d_in[11];
  const float* WL2 = (const float*)d_in[12];
  const float* GK2 = (const float*)d_in[13];
  const float* GRK2 = (const float*)d_in[14];
  const float* GB2 = (const float*)d_in[15];
  const float* A1W = (const float*)d_in[16];
  const float* A1B = (const float*)d_in[17];
  const float* A2W = (const float*)d_in[18];
  const float* A2B = (const float*)d_in[19];
  const float* WG = (const float*)d_in[20];
  const float* WOUT = (const float*)d_in[21];
  const float* BOUT = (const float*)d_in[22];

  float* ws = (float*)d_ws;
  float* wh = ws;            // 8388608 floats
  float* xp = wh + 8388608;  // 6291456
  unsigned int* whg = (unsigned int*)(xp + 6291456);  // 4194304 uints
  float* ah1 = (float*)(whg + 4194304);               // 65536
  float* ah2 = ah1 + 65536;                           // 65536
  float* e12 = ah2 + 65536;                           // 4096
  int* counts = (int*)(e12 + 4096);                   // 65536
  int* edges = counts + 65536;  // 4*16384*64 = 4194304

  k_data<<<1024, 64, 0, stream>>>(LIT1, SEM1, LIT2, SEM2, WL1, GK1, GB1, WL2,
                                  GK2, GB2, wh, xp);
  k_csr<<<1024, 256, 0, stream>>>(CFG1, CFG2, counts, edges);
  k_gru<<<64, 64, 0, stream>>>(xp, GRK1, GB1, GRK2, GB2, wh);
  for (int step = 0; step < 3; ++step) {
    k_whg<<<1024, 64, 0, stream>>>(wh, WG, A1W, A1B, A2W, A2B, whg, ah1, ah2);
    k_attn<<<16384, 256, 0, stream>>>(wh, whg, ah1, ah2, counts, edges);
  }
  k_tail<<<64, 256, 0, stream>>>(wh, WOUT, BOUT, e12);
  k_cos<<<1, 64, 0, stream>>>(e12, (float*)d_out);
}